// Round 6
// baseline (1679.346 us; speedup 1.0000x reference)
//
#include <hip/hip_runtime.h>

#define BB 16
#define PP 100
#define EE 5
#define DD 128
#define GG 10
#define PD 12800      // P*D
#define KTD 12900     // PD + P
#define BPD (BB*PD)   // floats per level slab

typedef __attribute__((ext_vector_type(4))) float f32x4;
typedef __attribute__((ext_vector_type(8))) short short8;
typedef __attribute__((ext_vector_type(4))) short short4v;

static __device__ __forceinline__ short f2bf(float f) {
  unsigned u = __builtin_bit_cast(unsigned, f);
  u += 0x7FFFu + ((u >> 16) & 1u);
  return (short)(u >> 16);
}

static __device__ __forceinline__ short8 cvt8(float4 a, float4 b) {
  short8 r;
  r[0] = f2bf(a.x); r[1] = f2bf(a.y); r[2] = f2bf(a.z); r[3] = f2bf(a.w);
  r[4] = f2bf(b.x); r[5] = f2bf(b.y); r[6] = f2bf(b.z); r[7] = f2bf(b.w);
  return r;
}

// ---------------- encoder: patches -> conv -> relu -> fc -> broadcast to 5 levels
__global__ __launch_bounds__(128) void k_encoder(
    const float* __restrict__ x, const float* __restrict__ cw, const float* __restrict__ cb,
    const float* __restrict__ fw, const float* __restrict__ fb, float* __restrict__ cols) {
  int bid = blockIdx.x;            // b*100 + p
  int b = bid / 100, p = bid % 100;
  int py = p / 10, px = p % 10;
  __shared__ float patch[9];
  __shared__ float h[32];
  int tid = threadIdx.x;
  if (tid < 9) {
    int ii = tid / 3, jj = tid % 3;
    int gr = py * 3 + ii - 1, gc = px * 3 + jj - 1;
    float v = 0.f;
    if (gr >= 0 && gr < 28 && gc >= 0 && gc < 28) v = x[b * 784 + gr * 28 + gc];
    patch[tid] = v;
  }
  __syncthreads();
  if (tid < 32) {
    float a = cb[tid];
#pragma unroll
    for (int t = 0; t < 9; ++t) a += patch[t] * cw[tid * 9 + t];
    h[tid] = fmaxf(a, 0.f);
  }
  __syncthreads();
  float e = fb[tid];
#pragma unroll
  for (int o = 0; o < 32; ++o) e += h[o] * fw[tid * 32 + o];
  long bp = (long)b * PP + p;
  for (int lev = 0; lev < EE; ++lev)
    cols[((long)lev * BB * PP + bp) * DD + tid] = e;
}

// ---------------- fold pos columns of td_w into bias (pos is constant = arange(P))
__global__ __launch_bounds__(256) void k_tdbias(
    const float* __restrict__ td_w, const float* __restrict__ td_b, float* __restrict__ out) {
  int o = blockIdx.x * 256 + threadIdx.x;
  if (o >= PD) return;
  float s = td_b[o];
  const float* r = td_w + (long)o * KTD + PD;
#pragma unroll 4
  for (int p = 0; p < 100; ++p) s += (float)p * r[p];
  out[o] = s;
}

#define MSTRIDE (1600L * 16 * 8)   // one 16-row block of packed A/W (shorts)

// ---------------- pack weights v4: barrier-free, write-coalesced, 4-deep prefetch
// grid 1600 (which*800 + rb). thread t: row r=t&15, kgroup kq=t>>4.
// Per iter: read 32B at (row, it*128 + kq*8); write 16B at tiled offset it*2048 + t*8.
__global__ __launch_bounds__(256) void k_packw(
    const float* __restrict__ td_w, const float* __restrict__ bu_w,
    short* __restrict__ wtd, short* __restrict__ wbu) {
  int bid = blockIdx.x;
  int which = bid / 800;
  int rb = bid % 800;
  const float* src = which ? bu_w : td_w;
  long ldw = which ? PD : KTD;
  int t = threadIdx.x;
  int r = t & 15, kq = t >> 4;
  const float* sp = src + ((long)rb * 16 + r) * ldw + kq * 8;
  short* dp = (which ? wbu : wtd) + (long)rb * MSTRIDE + (long)t * 8;
  float4 c0[4], c1[4];
#define PW_LD(s, off) { c0[s] = *(const float4*)(sp + (off)); c1[s] = *(const float4*)(sp + (off) + 4); }
  PW_LD(0, 0) PW_LD(1, 128) PW_LD(2, 256)
#define PW_IT(j) { \
  PW_LD(((j) + 3) & 3, 384) \
  *(short8*)dp = cvt8(c0[j], c1[j]); \
  sp += 128; dp += 2048; }
#define PW_ST(j) { *(short8*)dp = cvt8(c0[j], c1[j]); dp += 2048; }
  for (int kb = 0; kb < 24; ++kb) { PW_IT(0) PW_IT(1) PW_IT(2) PW_IT(3) }
  PW_IT(0)                    // it=96; its prefetch (sp+384) is it=99, last in-bounds chunk
  PW_ST(1) PW_ST(2) PW_ST(3)  // its 97..99: stores only, no loads past end
#undef PW_IT
#undef PW_ST
#undef PW_LD
}

// ---------------- pack activations (80 rows x 12800) f32 -> bf16 tiles
__global__ __launch_bounds__(256) void k_packa(
    const float* __restrict__ src, short* __restrict__ dst) {
  int bid = blockIdx.x;            // rb*8 + kc, RB=5
  int rb = bid / 8;
  int kc = bid % 8;
  int t = threadIdx.x;
  int r = t >> 4, c = t & 15;
  long srow = ((long)rb * 16 + r) * PD;
  for (int kk = 0; kk < 25; ++kk) {
    int k = kc * 1600 + kk * 64 + c * 4;
    float4 v = *(const float4*)(src + srow + k);
    short4v o;
    o[0] = f2bf(v.x); o[1] = f2bf(v.y); o[2] = f2bf(v.z); o[3] = f2bf(v.w);
    long di = (((long)rb * 1600 + (k >> 3)) * 16 + r) * 8 + (k & 7);
    *(short4v*)(dst + di) = o;
  }
}

// ---------------- packed bf16 GEMM: 256 threads, B 3-ahead (4 slots), A 2-ahead
__global__ __launch_bounds__(256) void k_gemm_p(
    const short* __restrict__ Ap, const short* __restrict__ wtd,
    const short* __restrict__ wbu, float* __restrict__ ytd, float* __restrict__ ybu) {
  int bid = blockIdx.x;            // which*800 + kc*200 + nb
  int which = bid / 800;
  int r = bid % 800;
  int kc = r / 200;
  int nb = r % 200;
  int wave = threadIdx.x >> 6;
  int lane = threadIdx.x & 63;
  int l15 = lane & 15, l4 = lane >> 4;
  int nb16 = nb * 4 + wave;
  const short* Wp = which ? wbu : wtd;
  float* Y = which ? ybu : ytd;
  int lev0 = which ? 0 : 1;
  long laneoff = (((long)kc * 400 + l4) * 16 + l15) * 8;
  const short* bp = Wp + (long)nb16 * MSTRIDE + laneoff;
  const short* a0 = Ap + (long)(lev0 + 0) * MSTRIDE + laneoff;
  const short* a1 = Ap + (long)(lev0 + 1) * MSTRIDE + laneoff;
  const short* a2 = Ap + (long)(lev0 + 2) * MSTRIDE + laneoff;
  const short* a3 = Ap + (long)(lev0 + 3) * MSTRIDE + laneoff;
  short8 B[4], A0[2], A1[2], A2[2], A3[2];
  B[0] = *(const short8*)(bp);
  B[1] = *(const short8*)(bp + 512);
  B[2] = *(const short8*)(bp + 1024);
  A0[0] = *(const short8*)(a0); A0[1] = *(const short8*)(a0 + 512);
  A1[0] = *(const short8*)(a1); A1[1] = *(const short8*)(a1 + 512);
  A2[0] = *(const short8*)(a2); A2[1] = *(const short8*)(a2 + 512);
  A3[0] = *(const short8*)(a3); A3[1] = *(const short8*)(a3 + 512);
  f32x4 acc0 = {0,0,0,0}, acc1 = {0,0,0,0}, acc2 = {0,0,0,0}, acc3 = {0,0,0,0};
#define GI(j) { \
  B[((j) + 3) & 3] = *(const short8*)(bp + 1536); \
  acc0 = __builtin_amdgcn_mfma_f32_16x16x32_bf16(A0[(j) & 1], B[(j) & 3], acc0, 0, 0, 0); \
  acc1 = __builtin_amdgcn_mfma_f32_16x16x32_bf16(A1[(j) & 1], B[(j) & 3], acc1, 0, 0, 0); \
  acc2 = __builtin_amdgcn_mfma_f32_16x16x32_bf16(A2[(j) & 1], B[(j) & 3], acc2, 0, 0, 0); \
  acc3 = __builtin_amdgcn_mfma_f32_16x16x32_bf16(A3[(j) & 1], B[(j) & 3], acc3, 0, 0, 0); \
  A0[(j) & 1] = *(const short8*)(a0 + 1024); \
  A1[(j) & 1] = *(const short8*)(a1 + 1024); \
  A2[(j) & 1] = *(const short8*)(a2 + 1024); \
  A3[(j) & 1] = *(const short8*)(a3 + 1024); \
  bp += 512; a0 += 512; a1 += 512; a2 += 512; a3 += 512; }
  for (int kb = 0; kb < 25; ++kb) { GI(0) GI(1) GI(2) GI(3) }
#undef GI
  float* yb = Y + (long)kc * 64 * PD;
  int col = nb16 * 16 + l15;
#pragma unroll
  for (int j = 0; j < 4; ++j) yb[(long)(0 * 16 + l4 * 4 + j) * PD + col] = acc0[j];
#pragma unroll
  for (int j = 0; j < 4; ++j) yb[(long)(1 * 16 + l4 * 4 + j) * PD + col] = acc1[j];
#pragma unroll
  for (int j = 0; j < 4; ++j) yb[(long)(2 * 16 + l4 * 4 + j) * PD + col] = acc2[j];
#pragma unroll
  for (int j = 0; j < 4; ++j) yb[(long)(3 * 16 + l4 * 4 + j) * PD + col] = acc3[j];
}

// ---------------- fallback f32-stream GEMM (used only if ws too small to pack)
__global__ __launch_bounds__(256) void k_gemm(
    const float* __restrict__ cols, const float* __restrict__ td_w,
    const float* __restrict__ bu_w, float* __restrict__ ytd, float* __restrict__ ybu) {
  int bid = blockIdx.x;            // 0..1599
  int which = bid / 800;
  int r = bid % 800;
  int kc = r / 200;
  int nb = r % 200;
  const float* X; const float* W; long ldw; float* Y;
  if (which == 0) { X = cols + BPD; W = td_w; ldw = KTD; Y = ytd; }
  else            { X = cols;       W = bu_w; ldw = PD;  Y = ybu; }
  int wave = threadIdx.x >> 6;
  int lane = threadIdx.x & 63;
  int l15 = lane & 15, l4 = lane >> 4;
  int n0 = nb * 64 + wave * 16;
  int k0 = kc * 3200 + l4 * 8;
  const float* ap = X + (long)l15 * PD + k0;
  const float* bp = W + (long)(n0 + l15) * ldw + k0;
  f32x4 acc[4] = {{0,0,0,0},{0,0,0,0},{0,0,0,0},{0,0,0,0}};
  for (int kk = 0; kk < 100; ++kk) {
    float4 b0 = *(const float4*)bp;
    float4 b1 = *(const float4*)(bp + 4);
    short8 bf = cvt8(b0, b1);
#pragma unroll
    for (int m = 0; m < 4; ++m) {
      const float* a_ = ap + (long)m * 16 * PD;
      float4 a0 = *(const float4*)a_;
      float4 a1 = *(const float4*)(a_ + 4);
      short8 af = cvt8(a0, a1);
      acc[m] = __builtin_amdgcn_mfma_f32_16x16x32_bf16(af, bf, acc[m], 0, 0, 0);
    }
    ap += 32; bp += 32;
  }
  float* yb = Y + (long)kc * 64 * PD;
  int col = n0 + l15;
#pragma unroll
  for (int m = 0; m < 4; ++m)
#pragma unroll
    for (int j = 0; j < 4; ++j)
      yb[(long)(m * 16 + l4 * 4 + j) * PD + col] = acc[m][j];
}

// ---------------- grouped 10x10 conv producing q (transposed), k, v
__global__ __launch_bounds__(128) void k_gconv(
    const float* __restrict__ cols,
    const float* __restrict__ qw, const float* __restrict__ qb,
    const float* __restrict__ kw, const float* __restrict__ kb,
    const float* __restrict__ vw, const float* __restrict__ vb,
    float* __restrict__ qT, float* __restrict__ kbuf, float* __restrict__ vbuf) {
  int bid = blockIdx.x;            // i*160 + b*10 + g
  int i = bid / 160;
  int r2 = bid % 160;
  int b = r2 / 10, g = r2 % 10;
  __shared__ float t1g[10][128];
  __shared__ float wq[100], wk[100], wv[100];
  int tid = threadIdx.x;
  const float* base = cols + ((long)(i * BB + b) * PP + g * 10) * DD;
  for (int idx = tid; idx < 1280; idx += 128) t1g[idx >> 7][idx & 127] = base[idx];
  if (tid < 100) {
    wq[tid] = qw[g * 100 + tid];
    wk[tid] = kw[g * 100 + tid];
    wv[tid] = vw[g * 100 + tid];
  }
  __syncthreads();
  int s = tid;
  long ib = (long)(i * BB + b);
  for (int o = 0; o < 10; ++o) {
    int p = g * 10 + o;
    float aq = qb[p], ak = kb[p], av = vb[p];
#pragma unroll
    for (int c = 0; c < 10; ++c) {
      float z = t1g[c][s];
      aq += wq[o * 10 + c] * z;
      ak += wk[o * 10 + c] * z;
      av += wv[o * 10 + c] * z;
    }
    qT[(ib * DD + s) * 100 + p] = aq;   // [ib][n=s][c=p]
    kbuf[(ib * PP + p) * DD + s] = ak;  // [ib][p][s]
    vbuf[(ib * PP + p) * DD + s] = av;
  }
}

// ---------------- logits + softmax over m: a[ib][n][m]
__global__ __launch_bounds__(256) void k_logits(
    const float* __restrict__ qT, const float* __restrict__ kbuf, float* __restrict__ abuf) {
  int bid = blockIdx.x;            // ib*4 + nq
  int ib = bid >> 2;
  int nq = bid & 3;
  __shared__ float klds[100 * 128];
  int tid = threadIdx.x;
  const float* kb_ = kbuf + (long)ib * PP * DD;
  for (int idx = tid; idx < PP * DD; idx += 256) klds[idx] = kb_[idx];
  __syncthreads();
  int wave = tid >> 6, lane = tid & 63;
  for (int nn = 0; nn < 8; ++nn) {
    int n = nq * 32 + nn * 4 + wave;
    const float* qrow = qT + ((long)ib * DD + n) * 100;
    float a1 = 0.f, a2 = 0.f;
#pragma unroll 4
    for (int c = 0; c < 100; ++c) {
      float qv = qrow[c];
      a1 += qv * klds[c * 128 + lane];
      a2 += qv * klds[c * 128 + 64 + lane];
    }
    float mx = fmaxf(a1, a2);
    for (int off = 32; off; off >>= 1) mx = fmaxf(mx, __shfl_xor(mx, off));
    float e1 = __expf(a1 - mx), e2 = __expf(a2 - mx);
    float sm = e1 + e2;
    for (int off = 32; off; off >>= 1) sm += __shfl_xor(sm, off);
    float inv = 1.0f / sm;
    float* arow = abuf + ((long)ib * DD + n) * DD;
    arow[lane] = e1 * inv;
    arow[64 + lane] = e2 * inv;
  }
}

// ---------------- O = V*A^T, then combine: c = 1.33*t1 + 0.33*gamma*O + 0.33*td + 0.33*bu
__global__ __launch_bounds__(256) void k_combine(
    const float* __restrict__ cols, const float* __restrict__ vbuf,
    const float* __restrict__ abuf, const float* __restrict__ ytd,
    const float* __restrict__ ybu, const float* __restrict__ tdbias,
    const float* __restrict__ bub, const float* __restrict__ gamma,
    float* __restrict__ colsn) {
  int bid = blockIdx.x;            // ib*2 + half
  int ib = bid >> 1;
  int half = bid & 1;
  int i = ib >> 4, b = ib & 15;
  __shared__ float aT[128 * 65];   // aT[m][n_local], stride 65 -> conflict-free
  int tid = threadIdx.x;
  const float* ag = abuf + (long)ib * DD * DD;
  for (int idx = tid; idx < 8192; idx += 256) {
    int m = idx & 127;
    int nl = idx >> 7;
    aT[m * 65 + nl] = ag[(long)(half * 64 + nl) * DD + m];
  }
  __syncthreads();
  float gam = gamma[0];
  const float* vb_ = vbuf + (long)ib * PP * DD;
  const float* t1b = cols + (long)ib * PD;
  float* outb = colsn + (long)ib * PD;
  bool has_td = (i < EE - 1);
  bool has_bu = (i > 0);
  const float* ytdr = ytd + ((long)i * BB + b) * PD;
  const float* ybur = ybu + ((long)(i - 1) * BB + b) * PD;
  const long CH = 64L * PD;        // kc-chunk stride in partial buffers
  for (int oi = tid; oi < 6400; oi += 256) {
    int p = oi >> 6;
    int nl = oi & 63;
    int n = half * 64 + nl;
    const float* vrow = vb_ + p * DD;
    float ov = 0.f;
#pragma unroll 4
    for (int m = 0; m < 128; ++m) ov += vrow[m] * aT[m * 65 + nl];
    int od = p * DD + n;
    float t1 = t1b[od];
    float accv = t1 + 0.33f * (gam * ov + t1);
    if (has_td) {
      float y = tdbias[od] + ytdr[od] + ytdr[CH + od] + ytdr[2 * CH + od] + ytdr[3 * CH + od];
      accv += 0.33f * y;
    }
    if (has_bu) {
      float y = bub[od] + ybur[od] + ybur[CH + od] + ybur[2 * CH + od] + ybur[3 * CH + od];
      accv += 0.33f * y;
    }
    outb[od] = accv;
  }
}

// ---------------- final: out[b][d] = mean_p cols[level 4][b][p][d]
__global__ __launch_bounds__(128) void k_mean(const float* __restrict__ cols, float* __restrict__ out) {
  int b = blockIdx.x, d = threadIdx.x;
  const float* base = cols + ((long)4 * BB + b) * PP * DD + d;
  float s = 0.f;
  for (int p = 0; p < PP; ++p) s += base[(long)p * DD];
  out[b * DD + d] = s / 100.0f;
}

extern "C" void kernel_launch(void* const* d_in, const int* in_sizes, int n_in,
                              void* d_out, int out_size, void* d_ws, size_t ws_size,
                              hipStream_t stream) {
  const float* x     = (const float*)d_in[0];
  const float* cnn_w = (const float*)d_in[1];
  const float* cnn_b = (const float*)d_in[2];
  const float* fc_w  = (const float*)d_in[3];
  const float* fc_b  = (const float*)d_in[4];
  const float* td_w  = (const float*)d_in[5];
  const float* td_b  = (const float*)d_in[6];
  const float* bu_w  = (const float*)d_in[7];
  const float* bu_b  = (const float*)d_in[8];
  const float* qw    = (const float*)d_in[9];
  const float* qb    = (const float*)d_in[10];
  const float* kw    = (const float*)d_in[11];
  const float* kb    = (const float*)d_in[12];
  const float* vw    = (const float*)d_in[13];
  const float* vb    = (const float*)d_in[14];
  const float* gamma = (const float*)d_in[15];
  float* out = (float*)d_out;
  float* ws = (float*)d_ws;

  float* cols_a = ws;                     // 1,024,000
  float* cols_b = ws + 1024000;           // 1,024,000
  float* qT     = ws + 2048000;           // 1,024,000
  float* kbuf   = ws + 3072000;           // 1,024,000
  float* vbuf   = ws + 4096000;           // 1,024,000
  float* abuf   = ws + 5120000;           // 1,310,720
  float* ytd    = ws + 6430720;           // 3,276,800
  float* ybu    = ws + 9707520;           // 3,276,800
  float* tdbias = ws + 12984320;          // 12,800
  // packed bf16 region (shorts)
  short* wtd_p  = (short*)(ws + 12997120);          // 163,840,000 shorts
  short* wbu_p  = wtd_p + 163840000;                // 163,840,000 shorts
  short* apack  = wbu_p + 163840000;                // 1,024,000 shorts (+8192 pad)
  size_t need_bytes = (size_t)12997120 * 4 + (163840000ULL * 2 + 1024000ULL + 8192ULL) * 2;
  bool packed = ws_size >= need_bytes;

  k_encoder<<<1600, 128, 0, stream>>>(x, cnn_w, cnn_b, fc_w, fc_b, cols_a);
  k_tdbias<<<50, 256, 0, stream>>>(td_w, td_b, tdbias);
  if (packed) k_packw<<<1600, 256, 0, stream>>>(td_w, bu_w, wtd_p, wbu_p);

  float* cur = cols_a;
  float* nxt = cols_b;
  for (int t = 0; t < 3; ++t) {
    if (packed) {
      k_packa<<<40, 256, 0, stream>>>(cur, apack);
      k_gemm_p<<<1600, 256, 0, stream>>>(apack, wtd_p, wbu_p, ytd, ybu);
    } else {
      k_gemm<<<1600, 256, 0, stream>>>(cur, td_w, bu_w, ytd, ybu);
    }
    k_gconv<<<800, 128, 0, stream>>>(cur, qw, qb, kw, kb, vw, vb, qT, kbuf, vbuf);
    k_logits<<<320, 256, 0, stream>>>(qT, kbuf, abuf);
    k_combine<<<160, 256, 0, stream>>>(cur, vbuf, abuf, ytd, ybu, tdbias, bu_b, gamma, nxt);
    float* tmp = cur; cur = nxt; nxt = tmp;
  }
  k_mean<<<16, 128, 0, stream>>>(cur, out);
}

// Round 7
// 1466.452 us; speedup vs baseline: 1.1452x; 1.1452x over previous
//
#include <hip/hip_runtime.h>

#define BB 16
#define PP 100
#define EE 5
#define DD 128
#define GG 10
#define PD 12800      // P*D
#define KTD 12900     // PD + P
#define BPD (BB*PD)   // floats per level slab

typedef __attribute__((ext_vector_type(4))) float f32x4;
typedef __attribute__((ext_vector_type(8))) short short8;
typedef __attribute__((ext_vector_type(4))) short short4v;

static __device__ __forceinline__ short f2bf(float f) {
  unsigned u = __builtin_bit_cast(unsigned, f);
  u += 0x7FFFu + ((u >> 16) & 1u);
  return (short)(u >> 16);
}

static __device__ __forceinline__ short8 cvt8(float4 a, float4 b) {
  short8 r;
  r[0] = f2bf(a.x); r[1] = f2bf(a.y); r[2] = f2bf(a.z); r[3] = f2bf(a.w);
  r[4] = f2bf(b.x); r[5] = f2bf(b.y); r[6] = f2bf(b.z); r[7] = f2bf(b.w);
  return r;
}

// fire-and-forget 16B global->LDS DMA. lds base must be wave-uniform; HW adds lane*16.
static __device__ __forceinline__ void gload16(const void* g, void* l) {
  __builtin_amdgcn_global_load_lds((const __attribute__((address_space(1))) void*)g,
                                   (__attribute__((address_space(3))) void*)l, 16, 0, 0);
}

// ---------------- encoder: patches -> conv -> relu -> fc -> broadcast to 5 levels
__global__ __launch_bounds__(128) void k_encoder(
    const float* __restrict__ x, const float* __restrict__ cw, const float* __restrict__ cb,
    const float* __restrict__ fw, const float* __restrict__ fb, float* __restrict__ cols) {
  int bid = blockIdx.x;            // b*100 + p
  int b = bid / 100, p = bid % 100;
  int py = p / 10, px = p % 10;
  __shared__ float patch[9];
  __shared__ float h[32];
  int tid = threadIdx.x;
  if (tid < 9) {
    int ii = tid / 3, jj = tid % 3;
    int gr = py * 3 + ii - 1, gc = px * 3 + jj - 1;
    float v = 0.f;
    if (gr >= 0 && gr < 28 && gc >= 0 && gc < 28) v = x[b * 784 + gr * 28 + gc];
    patch[tid] = v;
  }
  __syncthreads();
  if (tid < 32) {
    float a = cb[tid];
#pragma unroll
    for (int t = 0; t < 9; ++t) a += patch[t] * cw[tid * 9 + t];
    h[tid] = fmaxf(a, 0.f);
  }
  __syncthreads();
  float e = fb[tid];
#pragma unroll
  for (int o = 0; o < 32; ++o) e += h[o] * fw[tid * 32 + o];
  long bp = (long)b * PP + p;
  for (int lev = 0; lev < EE; ++lev)
    cols[((long)lev * BB * PP + bp) * DD + tid] = e;
}

// ---------------- fold pos columns of td_w into bias (pos is constant = arange(P))
__global__ __launch_bounds__(256) void k_tdbias(
    const float* __restrict__ td_w, const float* __restrict__ td_b, float* __restrict__ out) {
  int o = blockIdx.x * 256 + threadIdx.x;
  if (o >= PD) return;
  float s = td_b[o];
  const float* r = td_w + (long)o * KTD + PD;
#pragma unroll 4
  for (int p = 0; p < 100; ++p) s += (float)p * r[p];
  out[o] = s;
}

#define MSTRIDE (1600L * 16 * 8)   // one 16-row block of packed A/W (shorts)

// ---------------- pack weights v5: global_load_lds staged, XOR-swizzled LDS, tiled store
// grid 1600 (which*800 + rb). Per iter: stage [16 rows][128 floats] (row-contiguous
// 512B segments), read swizzled, cvt, one contiguous 4KB tiled store per block.
__global__ __launch_bounds__(256) void k_packw(
    const float* __restrict__ td_w, const float* __restrict__ bu_w,
    short* __restrict__ wtd, short* __restrict__ wbu) {
  int bid = blockIdx.x;
  int which = bid / 800;
  int rb = bid % 800;
  const float* src = which ? bu_w : td_w;
  long ldw = which ? PD : KTD;
  __shared__ float ldsf[2][2048];       // [16 rows][128 floats], 8KB per buf
  int t = threadIdx.x;
  int w = t >> 6;
  // stage source addrs (per-lane, pre-swizzled): pass p covers idx16 = p*256+t
  const float* srcP[2];
  int lo[2];
#pragma unroll
  for (int p = 0; p < 2; ++p) {
    int idx = p * 256 + t;
    int row = idx >> 5;                 // 0..15
    int rem = idx & 31;
    int c32o = (rem >> 1) ^ (row & 15); // inverse-swizzled source 32B unit
    int half = rem & 1;
    srcP[p] = src + ((long)(rb * 16 + row)) * ldw + c32o * 8 + half * 4;
    lo[p] = p * 1024 + w * 256;         // wave-uniform float offset (HW adds lane*16B)
  }
  short* dp = (which ? wbu : wtd) + (long)rb * MSTRIDE + (long)t * 8;
  int r = t & 15;
  int cswz = ((t >> 4) ^ r) * 8;        // swizzled read: orig kg_l = t>>4
  // prologue: stage it=0 into buf 0
  gload16(srcP[0], &ldsf[0][lo[0]]);
  gload16(srcP[1], &ldsf[0][lo[1]]);
  for (int it = 0; it < 100; ++it) {
    __syncthreads();                    // drains stage(it) for all waves
    if (it < 99) {
      int nb = (it + 1) & 1;
      gload16(srcP[0] + (it + 1) * 128, &ldsf[nb][lo[0]]);
      gload16(srcP[1] + (it + 1) * 128, &ldsf[nb][lo[1]]);
    }
    const float* bufp = ldsf[it & 1];
    float4 a = *(const float4*)&bufp[r * 128 + cswz];
    float4 b = *(const float4*)&bufp[r * 128 + cswz + 4];
    *(short8*)dp = cvt8(a, b);
    dp += 2048;
  }
}

// ---------------- pack activations (80 rows x 12800) f32 -> bf16 tiles
__global__ __launch_bounds__(256) void k_packa(
    const float* __restrict__ src, short* __restrict__ dst) {
  int bid = blockIdx.x;            // rb*8 + kc, RB=5
  int rb = bid / 8;
  int kc = bid % 8;
  int t = threadIdx.x;
  int r = t >> 4, c = t & 15;
  long srow = ((long)rb * 16 + r) * PD;
  for (int kk = 0; kk < 25; ++kk) {
    int k = kc * 1600 + kk * 64 + c * 4;
    float4 v = *(const float4*)(src + srow + k);
    short4v o;
    o[0] = f2bf(v.x); o[1] = f2bf(v.y); o[2] = f2bf(v.z); o[3] = f2bf(v.w);
    long di = (((long)rb * 1600 + (k >> 3)) * 16 + r) * 8 + (k & 7);
    *(short4v*)(dst + di) = o;
  }
}

// ---------------- packed bf16 GEMM v3: global_load_lds double-buffered staging
// Per stage (64 k): wave w stages B colgroup w (2KB) + A level w (2KB); compute
// phase is pure ds_read + MFMA. 50 stages per 3200-k chunk.
__global__ __launch_bounds__(256) void k_gemm_p(
    const short* __restrict__ Ap, const short* __restrict__ wtd,
    const short* __restrict__ wbu, float* __restrict__ ytd, float* __restrict__ ybu) {
  int bid = blockIdx.x;            // which*800 + kc*200 + nb
  int which = bid / 800;
  int r = bid % 800;
  int kc = r / 200;
  int nb = r % 200;
  int w = threadIdx.x >> 6;
  int lane = threadIdx.x & 63;
  int l15 = lane & 15, l4 = lane >> 4;
  const short* Wp = which ? wbu : wtd;
  float* Y = which ? ybu : ytd;
  int lev0 = which ? 0 : 1;
  int nb16 = nb * 4 + w;
  __shared__ short lA[2][4096];    // [level][kg 0..7][row 16][k 8]
  __shared__ short lB[2][4096];    // [colgroup][kg][col 16][k 8]
  const short* sB = Wp + (long)nb16 * MSTRIDE + (long)kc * 51200 + lane * 8;
  const short* sA = Ap + (long)(lev0 + w) * MSTRIDE + (long)kc * 51200 + lane * 8;
  int lbase = w * 1024;            // wave-uniform short offset (HW adds lane*16B)
#define STAGE_G(bufi) { \
  gload16(sB,       &lB[bufi][lbase]); \
  gload16(sB + 512, &lB[bufi][lbase + 512]); \
  gload16(sA,       &lA[bufi][lbase]); \
  gload16(sA + 512, &lA[bufi][lbase + 512]); \
  sB += 1024; sA += 1024; }
  STAGE_G(0)
  f32x4 acc0 = {0,0,0,0}, acc1 = {0,0,0,0}, acc2 = {0,0,0,0}, acc3 = {0,0,0,0};
  int fo = l4 * 128 + l15 * 8;     // frag offset within a [kg][16][8] quad-kg half
  for (int s = 0; s < 50; ++s) {
    __syncthreads();               // stage(s) complete for all waves
    int cur = s & 1;
    if (s < 49) STAGE_G(cur ^ 1)
#pragma unroll
    for (int ks = 0; ks < 2; ++ks) {
      int off = ks * 512 + fo;
      short8 bF = *(const short8*)&lB[cur][w * 1024 + off];
      short8 a0 = *(const short8*)&lA[cur][0 * 1024 + off];
      short8 a1 = *(const short8*)&lA[cur][1 * 1024 + off];
      short8 a2 = *(const short8*)&lA[cur][2 * 1024 + off];
      short8 a3 = *(const short8*)&lA[cur][3 * 1024 + off];
      acc0 = __builtin_amdgcn_mfma_f32_16x16x32_bf16(a0, bF, acc0, 0, 0, 0);
      acc1 = __builtin_amdgcn_mfma_f32_16x16x32_bf16(a1, bF, acc1, 0, 0, 0);
      acc2 = __builtin_amdgcn_mfma_f32_16x16x32_bf16(a2, bF, acc2, 0, 0, 0);
      acc3 = __builtin_amdgcn_mfma_f32_16x16x32_bf16(a3, bF, acc3, 0, 0, 0);
    }
  }
#undef STAGE_G
  float* yb = Y + (long)kc * 64 * PD;
  int col = nb16 * 16 + l15;
#pragma unroll
  for (int j = 0; j < 4; ++j) yb[(long)(0 * 16 + l4 * 4 + j) * PD + col] = acc0[j];
#pragma unroll
  for (int j = 0; j < 4; ++j) yb[(long)(1 * 16 + l4 * 4 + j) * PD + col] = acc1[j];
#pragma unroll
  for (int j = 0; j < 4; ++j) yb[(long)(2 * 16 + l4 * 4 + j) * PD + col] = acc2[j];
#pragma unroll
  for (int j = 0; j < 4; ++j) yb[(long)(3 * 16 + l4 * 4 + j) * PD + col] = acc3[j];
}

// ---------------- fallback f32-stream GEMM (used only if ws too small to pack)
__global__ __launch_bounds__(256) void k_gemm(
    const float* __restrict__ cols, const float* __restrict__ td_w,
    const float* __restrict__ bu_w, float* __restrict__ ytd, float* __restrict__ ybu) {
  int bid = blockIdx.x;            // 0..1599
  int which = bid / 800;
  int r = bid % 800;
  int kc = r / 200;
  int nb = r % 200;
  const float* X; const float* W; long ldw; float* Y;
  if (which == 0) { X = cols + BPD; W = td_w; ldw = KTD; Y = ytd; }
  else            { X = cols;       W = bu_w; ldw = PD;  Y = ybu; }
  int wave = threadIdx.x >> 6;
  int lane = threadIdx.x & 63;
  int l15 = lane & 15, l4 = lane >> 4;
  int n0 = nb * 64 + wave * 16;
  int k0 = kc * 3200 + l4 * 8;
  const float* ap = X + (long)l15 * PD + k0;
  const float* bp = W + (long)(n0 + l15) * ldw + k0;
  f32x4 acc[4] = {{0,0,0,0},{0,0,0,0},{0,0,0,0},{0,0,0,0}};
  for (int kk = 0; kk < 100; ++kk) {
    float4 b0 = *(const float4*)bp;
    float4 b1 = *(const float4*)(bp + 4);
    short8 bf = cvt8(b0, b1);
#pragma unroll
    for (int m = 0; m < 4; ++m) {
      const float* a_ = ap + (long)m * 16 * PD;
      float4 a0 = *(const float4*)a_;
      float4 a1 = *(const float4*)(a_ + 4);
      short8 af = cvt8(a0, a1);
      acc[m] = __builtin_amdgcn_mfma_f32_16x16x32_bf16(af, bf, acc[m], 0, 0, 0);
    }
    ap += 32; bp += 32;
  }
  float* yb = Y + (long)kc * 64 * PD;
  int col = n0 + l15;
#pragma unroll
  for (int m = 0; m < 4; ++m)
#pragma unroll
    for (int j = 0; j < 4; ++j)
      yb[(long)(m * 16 + l4 * 4 + j) * PD + col] = acc[m][j];
}

// ---------------- grouped 10x10 conv producing q (transposed), k, v
__global__ __launch_bounds__(128) void k_gconv(
    const float* __restrict__ cols,
    const float* __restrict__ qw, const float* __restrict__ qb,
    const float* __restrict__ kw, const float* __restrict__ kb,
    const float* __restrict__ vw, const float* __restrict__ vb,
    float* __restrict__ qT, float* __restrict__ kbuf, float* __restrict__ vbuf) {
  int bid = blockIdx.x;            // i*160 + b*10 + g
  int i = bid / 160;
  int r2 = bid % 160;
  int b = r2 / 10, g = r2 % 10;
  __shared__ float t1g[10][128];
  __shared__ float wq[100], wk[100], wv[100];
  int tid = threadIdx.x;
  const float* base = cols + ((long)(i * BB + b) * PP + g * 10) * DD;
  for (int idx = tid; idx < 1280; idx += 128) t1g[idx >> 7][idx & 127] = base[idx];
  if (tid < 100) {
    wq[tid] = qw[g * 100 + tid];
    wk[tid] = kw[g * 100 + tid];
    wv[tid] = vw[g * 100 + tid];
  }
  __syncthreads();
  int s = tid;
  long ib = (long)(i * BB + b);
  for (int o = 0; o < 10; ++o) {
    int p = g * 10 + o;
    float aq = qb[p], ak = kb[p], av = vb[p];
#pragma unroll
    for (int c = 0; c < 10; ++c) {
      float z = t1g[c][s];
      aq += wq[o * 10 + c] * z;
      ak += wk[o * 10 + c] * z;
      av += wv[o * 10 + c] * z;
    }
    qT[(ib * DD + s) * 100 + p] = aq;   // [ib][n=s][c=p]
    kbuf[(ib * PP + p) * DD + s] = ak;  // [ib][p][s]
    vbuf[(ib * PP + p) * DD + s] = av;
  }
}

// ---------------- logits + softmax over m: a[ib][n][m]
__global__ __launch_bounds__(256) void k_logits(
    const float* __restrict__ qT, const float* __restrict__ kbuf, float* __restrict__ abuf) {
  int bid = blockIdx.x;            // ib*4 + nq
  int ib = bid >> 2;
  int nq = bid & 3;
  __shared__ float klds[100 * 128];
  int tid = threadIdx.x;
  const float* kb_ = kbuf + (long)ib * PP * DD;
  for (int idx = tid; idx < PP * DD; idx += 256) klds[idx] = kb_[idx];
  __syncthreads();
  int wave = tid >> 6, lane = tid & 63;
  for (int nn = 0; nn < 8; ++nn) {
    int n = nq * 32 + nn * 4 + wave;
    const float* qrow = qT + ((long)ib * DD + n) * 100;
    float a1 = 0.f, a2 = 0.f;
#pragma unroll 4
    for (int c = 0; c < 100; ++c) {
      float qv = qrow[c];
      a1 += qv * klds[c * 128 + lane];
      a2 += qv * klds[c * 128 + 64 + lane];
    }
    float mx = fmaxf(a1, a2);
    for (int off = 32; off; off >>= 1) mx = fmaxf(mx, __shfl_xor(mx, off));
    float e1 = __expf(a1 - mx), e2 = __expf(a2 - mx);
    float sm = e1 + e2;
    for (int off = 32; off; off >>= 1) sm += __shfl_xor(sm, off);
    float inv = 1.0f / sm;
    float* arow = abuf + ((long)ib * DD + n) * DD;
    arow[lane] = e1 * inv;
    arow[64 + lane] = e2 * inv;
  }
}

// ---------------- O = V*A^T, then combine: c = 1.33*t1 + 0.33*gamma*O + 0.33*td + 0.33*bu
__global__ __launch_bounds__(256) void k_combine(
    const float* __restrict__ cols, const float* __restrict__ vbuf,
    const float* __restrict__ abuf, const float* __restrict__ ytd,
    const float* __restrict__ ybu, const float* __restrict__ tdbias,
    const float* __restrict__ bub, const float* __restrict__ gamma,
    float* __restrict__ colsn) {
  int bid = blockIdx.x;            // ib*2 + half
  int ib = bid >> 1;
  int half = bid & 1;
  int i = ib >> 4, b = ib & 15;
  __shared__ float aT[128 * 65];   // aT[m][n_local], stride 65 -> conflict-free
  int tid = threadIdx.x;
  const float* ag = abuf + (long)ib * DD * DD;
  for (int idx = tid; idx < 8192; idx += 256) {
    int m = idx & 127;
    int nl = idx >> 7;
    aT[m * 65 + nl] = ag[(long)(half * 64 + nl) * DD + m];
  }
  __syncthreads();
  float gam = gamma[0];
  const float* vb_ = vbuf + (long)ib * PP * DD;
  const float* t1b = cols + (long)ib * PD;
  float* outb = colsn + (long)ib * PD;
  bool has_td = (i < EE - 1);
  bool has_bu = (i > 0);
  const float* ytdr = ytd + ((long)i * BB + b) * PD;
  const float* ybur = ybu + ((long)(i - 1) * BB + b) * PD;
  const long CH = 64L * PD;        // kc-chunk stride in partial buffers
  for (int oi = tid; oi < 6400; oi += 256) {
    int p = oi >> 6;
    int nl = oi & 63;
    int n = half * 64 + nl;
    const float* vrow = vb_ + p * DD;
    float ov = 0.f;
#pragma unroll 4
    for (int m = 0; m < 128; ++m) ov += vrow[m] * aT[m * 65 + nl];
    int od = p * DD + n;
    float t1 = t1b[od];
    float accv = t1 + 0.33f * (gam * ov + t1);
    if (has_td) {
      float y = tdbias[od] + ytdr[od] + ytdr[CH + od] + ytdr[2 * CH + od] + ytdr[3 * CH + od];
      accv += 0.33f * y;
    }
    if (has_bu) {
      float y = bub[od] + ybur[od] + ybur[CH + od] + ybur[2 * CH + od] + ybur[3 * CH + od];
      accv += 0.33f * y;
    }
    outb[od] = accv;
  }
}

// ---------------- final: out[b][d] = mean_p cols[level 4][b][p][d]
__global__ __launch_bounds__(128) void k_mean(const float* __restrict__ cols, float* __restrict__ out) {
  int b = blockIdx.x, d = threadIdx.x;
  const float* base = cols + ((long)4 * BB + b) * PP * DD + d;
  float s = 0.f;
  for (int p = 0; p < PP; ++p) s += base[(long)p * DD];
  out[b * DD + d] = s / 100.0f;
}

extern "C" void kernel_launch(void* const* d_in, const int* in_sizes, int n_in,
                              void* d_out, int out_size, void* d_ws, size_t ws_size,
                              hipStream_t stream) {
  const float* x     = (const float*)d_in[0];
  const float* cnn_w = (const float*)d_in[1];
  const float* cnn_b = (const float*)d_in[2];
  const float* fc_w  = (const float*)d_in[3];
  const float* fc_b  = (const float*)d_in[4];
  const float* td_w  = (const float*)d_in[5];
  const float* td_b  = (const float*)d_in[6];
  const float* bu_w  = (const float*)d_in[7];
  const float* bu_b  = (const float*)d_in[8];
  const float* qw    = (const float*)d_in[9];
  const float* qb    = (const float*)d_in[10];
  const float* kw    = (const float*)d_in[11];
  const float* kb    = (const float*)d_in[12];
  const float* vw    = (const float*)d_in[13];
  const float* vb    = (const float*)d_in[14];
  const float* gamma = (const float*)d_in[15];
  float* out = (float*)d_out;
  float* ws = (float*)d_ws;

  float* cols_a = ws;                     // 1,024,000
  float* cols_b = ws + 1024000;           // 1,024,000
  float* qT     = ws + 2048000;           // 1,024,000
  float* kbuf   = ws + 3072000;           // 1,024,000
  float* vbuf   = ws + 4096000;           // 1,024,000
  float* abuf   = ws + 5120000;           // 1,310,720
  float* ytd    = ws + 6430720;           // 3,276,800
  float* ybu    = ws + 9707520;           // 3,276,800
  float* tdbias = ws + 12984320;          // 12,800
  // packed bf16 region (shorts)
  short* wtd_p  = (short*)(ws + 12997120);          // 163,840,000 shorts
  short* wbu_p  = wtd_p + 163840000;                // 163,840,000 shorts
  short* apack  = wbu_p + 163840000;                // 1,024,000 shorts (+8192 pad)
  size_t need_bytes = (size_t)12997120 * 4 + (163840000ULL * 2 + 1024000ULL + 8192ULL) * 2;
  bool packed = ws_size >= need_bytes;

  k_encoder<<<1600, 128, 0, stream>>>(x, cnn_w, cnn_b, fc_w, fc_b, cols_a);
  k_tdbias<<<50, 256, 0, stream>>>(td_w, td_b, tdbias);
  if (packed) k_packw<<<1600, 256, 0, stream>>>(td_w, bu_w, wtd_p, wbu_p);

  float* cur = cols_a;
  float* nxt = cols_b;
  for (int t = 0; t < 3; ++t) {
    if (packed) {
      k_packa<<<40, 256, 0, stream>>>(cur, apack);
      k_gemm_p<<<1600, 256, 0, stream>>>(apack, wtd_p, wbu_p, ytd, ybu);
    } else {
      k_gemm<<<1600, 256, 0, stream>>>(cur, td_w, bu_w, ytd, ybu);
    }
    k_gconv<<<800, 128, 0, stream>>>(cur, qw, qb, kw, kb, vw, vb, qT, kbuf, vbuf);
    k_logits<<<320, 256, 0, stream>>>(qT, kbuf, abuf);
    k_combine<<<160, 256, 0, stream>>>(cur, vbuf, abuf, ytd, ybu, tdbias, bu_b, gamma, nxt);
    float* tmp = cur; cur = nxt; nxt = tmp;
  }
  k_mean<<<16, 128, 0, stream>>>(cur, out);
}

// Round 8
// 1369.795 us; speedup vs baseline: 1.2260x; 1.0706x over previous
//
#include <hip/hip_runtime.h>

#define BB 16
#define PP 100
#define EE 5
#define DD 128
#define GG 10
#define PD 12800      // P*D
#define KTD 12900     // PD + P
#define BPD (BB*PD)   // floats per level slab

typedef __attribute__((ext_vector_type(4))) float f32x4;
typedef __attribute__((ext_vector_type(8))) short short8;
typedef __attribute__((ext_vector_type(4))) short short4v;

static __device__ __forceinline__ short f2bf(float f) {
  unsigned u = __builtin_bit_cast(unsigned, f);
  u += 0x7FFFu + ((u >> 16) & 1u);
  return (short)(u >> 16);
}

static __device__ __forceinline__ short8 cvt8(float4 a, float4 b) {
  short8 r;
  r[0] = f2bf(a.x); r[1] = f2bf(a.y); r[2] = f2bf(a.z); r[3] = f2bf(a.w);
  r[4] = f2bf(b.x); r[5] = f2bf(b.y); r[6] = f2bf(b.z); r[7] = f2bf(b.w);
  return r;
}

// fire-and-forget global->LDS DMA. lds base must be wave-uniform; HW adds lane*size.
static __device__ __forceinline__ void gload16(const void* g, void* l) {
  __builtin_amdgcn_global_load_lds((const __attribute__((address_space(1))) void*)g,
                                   (__attribute__((address_space(3))) void*)l, 16, 0, 0);
}
static __device__ __forceinline__ void gload4(const void* g, void* l) {
  __builtin_amdgcn_global_load_lds((const __attribute__((address_space(1))) void*)g,
                                   (__attribute__((address_space(3))) void*)l, 4, 0, 0);
}

// ---------------- encoder: patches -> conv -> relu -> fc -> broadcast to 5 levels
__global__ __launch_bounds__(128) void k_encoder(
    const float* __restrict__ x, const float* __restrict__ cw, const float* __restrict__ cb,
    const float* __restrict__ fw, const float* __restrict__ fb, float* __restrict__ cols) {
  int bid = blockIdx.x;            // b*100 + p
  int b = bid / 100, p = bid % 100;
  int py = p / 10, px = p % 10;
  __shared__ float patch[9];
  __shared__ float h[32];
  int tid = threadIdx.x;
  if (tid < 9) {
    int ii = tid / 3, jj = tid % 3;
    int gr = py * 3 + ii - 1, gc = px * 3 + jj - 1;
    float v = 0.f;
    if (gr >= 0 && gr < 28 && gc >= 0 && gc < 28) v = x[b * 784 + gr * 28 + gc];
    patch[tid] = v;
  }
  __syncthreads();
  if (tid < 32) {
    float a = cb[tid];
#pragma unroll
    for (int t = 0; t < 9; ++t) a += patch[t] * cw[tid * 9 + t];
    h[tid] = fmaxf(a, 0.f);
  }
  __syncthreads();
  float e = fb[tid];
#pragma unroll
  for (int o = 0; o < 32; ++o) e += h[o] * fw[tid * 32 + o];
  long bp = (long)b * PP + p;
  for (int lev = 0; lev < EE; ++lev)
    cols[((long)lev * BB * PP + bp) * DD + tid] = e;
}

// ---------------- fold pos columns of td_w into bias (pos is constant = arange(P))
__global__ __launch_bounds__(256) void k_tdbias(
    const float* __restrict__ td_w, const float* __restrict__ td_b, float* __restrict__ out) {
  int o = blockIdx.x * 256 + threadIdx.x;
  if (o >= PD) return;
  float s = td_b[o];
  const float* r = td_w + (long)o * KTD + PD;
#pragma unroll 4
  for (int p = 0; p < 100; ++p) s += (float)p * r[p];
  out[o] = s;
}

#define MSTRIDE (1600L * 16 * 8)   // one 16-row block of packed A/W (shorts)

// ---------------- pack activations (80 rows x 12800) f32 -> bf16 tiles
__global__ __launch_bounds__(256) void k_packa(
    const float* __restrict__ src, short* __restrict__ dst) {
  int bid = blockIdx.x;            // rb*8 + kc, RB=5
  int rb = bid / 8;
  int kc = bid % 8;
  int t = threadIdx.x;
  int r = t >> 4, c = t & 15;
  long srow = ((long)rb * 16 + r) * PD;
  for (int kk = 0; kk < 25; ++kk) {
    int k = kc * 1600 + kk * 64 + c * 4;
    float4 v = *(const float4*)(src + srow + k);
    short4v o;
    o[0] = f2bf(v.x); o[1] = f2bf(v.y); o[2] = f2bf(v.z); o[3] = f2bf(v.w);
    long di = (((long)rb * 1600 + (k >> 3)) * 16 + r) * 8 + (k & 7);
    *(short4v*)(dst + di) = o;
  }
}

// ---------------- step-0 fused GEMM: stage f32 weights via gload4 (xor-swizzled src),
// convert in compute phase, MFMA, AND emit packed bf16 weights for steps 1-2.
__global__ __launch_bounds__(256) void k_gemm_f(
    const float* __restrict__ td_w, const float* __restrict__ bu_w,
    const short* __restrict__ Ap, short* __restrict__ wtd, short* __restrict__ wbu,
    float* __restrict__ ytd, float* __restrict__ ybu) {
  int bid = blockIdx.x;            // which*800 + kc*200 + nb
  int which = bid / 800;
  int r = bid % 800;
  int kc = r / 200;
  int nb = r % 200;
  int w = threadIdx.x >> 6;
  int lane = threadIdx.x & 63;
  int l15 = lane & 15, l4 = lane >> 4;
  const float* W = which ? bu_w : td_w;
  long ldw = which ? PD : KTD;
  short* WP = which ? wbu : wtd;
  float* Y = which ? ybu : ytd;
  int lev0 = which ? 0 : 1;
  int nb16 = nb * 4 + w;
  __shared__ float lBf[2][4096];   // per wave: [col 16][k 64] f32, k xor-swizzled by col
  __shared__ short lA[2][4096];    // [level][kg 0..7][row 16][k 8] bf16
  // B source pointers, one per col; per-lane k pre-swizzled: lane ^ ((c&7)*8)
  const float* bsrc[16];
#pragma unroll
  for (int c = 0; c < 16; ++c)
    bsrc[c] = W + (long)(nb16 * 16 + c) * ldw + kc * 3200 + (lane ^ ((c & 7) * 8));
  const short* sA = Ap + (long)(lev0 + w) * MSTRIDE + (long)kc * 51200 + lane * 8;
  short* wp = WP + (long)nb16 * MSTRIDE + (((long)kc * 400 + l4) * 16 + l15) * 8;
  int lbase = w * 1024;            // wave-uniform offset (floats / shorts)
#define STAGE_F(bufi) { \
  float* bdst = lBf[bufi]; short* adst = lA[bufi]; \
  _Pragma("unroll") \
  for (int c = 0; c < 16; ++c) gload4(bsrc[c], bdst + lbase + c * 64); \
  gload16(sA, adst + lbase); \
  gload16(sA + 512, adst + lbase + 512); \
  _Pragma("unroll") \
  for (int c = 0; c < 16; ++c) bsrc[c] += 64; \
  sA += 1024; }
  STAGE_F(0)
  f32x4 acc0 = {0,0,0,0}, acc1 = {0,0,0,0}, acc2 = {0,0,0,0}, acc3 = {0,0,0,0};
  int bswz = (l15 & 7) * 8;
  for (int s = 0; s < 50; ++s) {
    __syncthreads();               // stage(s) landed for all waves
    int cur = s & 1;
    if (s < 49) STAGE_F(cur ^ 1)
#pragma unroll
    for (int ks = 0; ks < 2; ++ks) {
      int fb_ = lbase + l15 * 64 + ((ks * 32 + l4 * 8) ^ bswz);
      float4 b0 = *(const float4*)&lBf[cur][fb_];
      float4 b1 = *(const float4*)&lBf[cur][fb_ + 4];
      short8 bF = cvt8(b0, b1);
      *(short8*)(wp + (long)(s * 8 + ks * 4) * 128) = bF;   // emit packed weights
      int off = ks * 512 + l4 * 128 + l15 * 8;
      short8 a0 = *(const short8*)&lA[cur][0 * 1024 + off];
      short8 a1 = *(const short8*)&lA[cur][1 * 1024 + off];
      short8 a2 = *(const short8*)&lA[cur][2 * 1024 + off];
      short8 a3 = *(const short8*)&lA[cur][3 * 1024 + off];
      acc0 = __builtin_amdgcn_mfma_f32_16x16x32_bf16(a0, bF, acc0, 0, 0, 0);
      acc1 = __builtin_amdgcn_mfma_f32_16x16x32_bf16(a1, bF, acc1, 0, 0, 0);
      acc2 = __builtin_amdgcn_mfma_f32_16x16x32_bf16(a2, bF, acc2, 0, 0, 0);
      acc3 = __builtin_amdgcn_mfma_f32_16x16x32_bf16(a3, bF, acc3, 0, 0, 0);
    }
  }
#undef STAGE_F
  float* yb = Y + (long)kc * 64 * PD;
  int col = nb16 * 16 + l15;
#pragma unroll
  for (int j = 0; j < 4; ++j) yb[(long)(0 * 16 + l4 * 4 + j) * PD + col] = acc0[j];
#pragma unroll
  for (int j = 0; j < 4; ++j) yb[(long)(1 * 16 + l4 * 4 + j) * PD + col] = acc1[j];
#pragma unroll
  for (int j = 0; j < 4; ++j) yb[(long)(2 * 16 + l4 * 4 + j) * PD + col] = acc2[j];
#pragma unroll
  for (int j = 0; j < 4; ++j) yb[(long)(3 * 16 + l4 * 4 + j) * PD + col] = acc3[j];
}

// ---------------- packed bf16 GEMM: global_load_lds double-buffered staging
__global__ __launch_bounds__(256) void k_gemm_p(
    const short* __restrict__ Ap, const short* __restrict__ wtd,
    const short* __restrict__ wbu, float* __restrict__ ytd, float* __restrict__ ybu) {
  int bid = blockIdx.x;            // which*800 + kc*200 + nb
  int which = bid / 800;
  int r = bid % 800;
  int kc = r / 200;
  int nb = r % 200;
  int w = threadIdx.x >> 6;
  int lane = threadIdx.x & 63;
  int l15 = lane & 15, l4 = lane >> 4;
  const short* Wp = which ? wbu : wtd;
  float* Y = which ? ybu : ytd;
  int lev0 = which ? 0 : 1;
  int nb16 = nb * 4 + w;
  __shared__ short lA[2][4096];
  __shared__ short lB[2][4096];
  const short* sB = Wp + (long)nb16 * MSTRIDE + (long)kc * 51200 + lane * 8;
  const short* sA = Ap + (long)(lev0 + w) * MSTRIDE + (long)kc * 51200 + lane * 8;
  int lbase = w * 1024;
#define STAGE_G(bufi) { \
  gload16(sB,       &lB[bufi][lbase]); \
  gload16(sB + 512, &lB[bufi][lbase + 512]); \
  gload16(sA,       &lA[bufi][lbase]); \
  gload16(sA + 512, &lA[bufi][lbase + 512]); \
  sB += 1024; sA += 1024; }
  STAGE_G(0)
  f32x4 acc0 = {0,0,0,0}, acc1 = {0,0,0,0}, acc2 = {0,0,0,0}, acc3 = {0,0,0,0};
  int fo = l4 * 128 + l15 * 8;
  for (int s = 0; s < 50; ++s) {
    __syncthreads();
    int cur = s & 1;
    if (s < 49) STAGE_G(cur ^ 1)
#pragma unroll
    for (int ks = 0; ks < 2; ++ks) {
      int off = ks * 512 + fo;
      short8 bF = *(const short8*)&lB[cur][w * 1024 + off];
      short8 a0 = *(const short8*)&lA[cur][0 * 1024 + off];
      short8 a1 = *(const short8*)&lA[cur][1 * 1024 + off];
      short8 a2 = *(const short8*)&lA[cur][2 * 1024 + off];
      short8 a3 = *(const short8*)&lA[cur][3 * 1024 + off];
      acc0 = __builtin_amdgcn_mfma_f32_16x16x32_bf16(a0, bF, acc0, 0, 0, 0);
      acc1 = __builtin_amdgcn_mfma_f32_16x16x32_bf16(a1, bF, acc1, 0, 0, 0);
      acc2 = __builtin_amdgcn_mfma_f32_16x16x32_bf16(a2, bF, acc2, 0, 0, 0);
      acc3 = __builtin_amdgcn_mfma_f32_16x16x32_bf16(a3, bF, acc3, 0, 0, 0);
    }
  }
#undef STAGE_G
  float* yb = Y + (long)kc * 64 * PD;
  int col = nb16 * 16 + l15;
#pragma unroll
  for (int j = 0; j < 4; ++j) yb[(long)(0 * 16 + l4 * 4 + j) * PD + col] = acc0[j];
#pragma unroll
  for (int j = 0; j < 4; ++j) yb[(long)(1 * 16 + l4 * 4 + j) * PD + col] = acc1[j];
#pragma unroll
  for (int j = 0; j < 4; ++j) yb[(long)(2 * 16 + l4 * 4 + j) * PD + col] = acc2[j];
#pragma unroll
  for (int j = 0; j < 4; ++j) yb[(long)(3 * 16 + l4 * 4 + j) * PD + col] = acc3[j];
}

// ---------------- fallback f32-stream GEMM (used only if ws too small to pack)
__global__ __launch_bounds__(256) void k_gemm(
    const float* __restrict__ cols, const float* __restrict__ td_w,
    const float* __restrict__ bu_w, float* __restrict__ ytd, float* __restrict__ ybu) {
  int bid = blockIdx.x;            // 0..1599
  int which = bid / 800;
  int r = bid % 800;
  int kc = r / 200;
  int nb = r % 200;
  const float* X; const float* W; long ldw; float* Y;
  if (which == 0) { X = cols + BPD; W = td_w; ldw = KTD; Y = ytd; }
  else            { X = cols;       W = bu_w; ldw = PD;  Y = ybu; }
  int wave = threadIdx.x >> 6;
  int lane = threadIdx.x & 63;
  int l15 = lane & 15, l4 = lane >> 4;
  int n0 = nb * 64 + wave * 16;
  int k0 = kc * 3200 + l4 * 8;
  const float* ap = X + (long)l15 * PD + k0;
  const float* bp = W + (long)(n0 + l15) * ldw + k0;
  f32x4 acc[4] = {{0,0,0,0},{0,0,0,0},{0,0,0,0},{0,0,0,0}};
  for (int kk = 0; kk < 100; ++kk) {
    float4 b0 = *(const float4*)bp;
    float4 b1 = *(const float4*)(bp + 4);
    short8 bf = cvt8(b0, b1);
#pragma unroll
    for (int m = 0; m < 4; ++m) {
      const float* a_ = ap + (long)m * 16 * PD;
      float4 a0 = *(const float4*)a_;
      float4 a1 = *(const float4*)(a_ + 4);
      short8 af = cvt8(a0, a1);
      acc[m] = __builtin_amdgcn_mfma_f32_16x16x32_bf16(af, bf, acc[m], 0, 0, 0);
    }
    ap += 32; bp += 32;
  }
  float* yb = Y + (long)kc * 64 * PD;
  int col = n0 + l15;
#pragma unroll
  for (int m = 0; m < 4; ++m)
#pragma unroll
    for (int j = 0; j < 4; ++j)
      yb[(long)(m * 16 + l4 * 4 + j) * PD + col] = acc[m][j];
}

// ---------------- grouped 10x10 conv producing q (transposed), k, v
__global__ __launch_bounds__(128) void k_gconv(
    const float* __restrict__ cols,
    const float* __restrict__ qw, const float* __restrict__ qb,
    const float* __restrict__ kw, const float* __restrict__ kb,
    const float* __restrict__ vw, const float* __restrict__ vb,
    float* __restrict__ qT, float* __restrict__ kbuf, float* __restrict__ vbuf) {
  int bid = blockIdx.x;            // i*160 + b*10 + g
  int i = bid / 160;
  int r2 = bid % 160;
  int b = r2 / 10, g = r2 % 10;
  __shared__ float t1g[10][128];
  __shared__ float wq[100], wk[100], wv[100];
  int tid = threadIdx.x;
  const float* base = cols + ((long)(i * BB + b) * PP + g * 10) * DD;
  for (int idx = tid; idx < 1280; idx += 128) t1g[idx >> 7][idx & 127] = base[idx];
  if (tid < 100) {
    wq[tid] = qw[g * 100 + tid];
    wk[tid] = kw[g * 100 + tid];
    wv[tid] = vw[g * 100 + tid];
  }
  __syncthreads();
  int s = tid;
  long ib = (long)(i * BB + b);
  for (int o = 0; o < 10; ++o) {
    int p = g * 10 + o;
    float aq = qb[p], ak = kb[p], av = vb[p];
#pragma unroll
    for (int c = 0; c < 10; ++c) {
      float z = t1g[c][s];
      aq += wq[o * 10 + c] * z;
      ak += wk[o * 10 + c] * z;
      av += wv[o * 10 + c] * z;
    }
    qT[(ib * DD + s) * 100 + p] = aq;   // [ib][n=s][c=p]
    kbuf[(ib * PP + p) * DD + s] = ak;  // [ib][p][s]
    vbuf[(ib * PP + p) * DD + s] = av;
  }
}

// ---------------- logits + softmax over m: a[ib][n][m]
__global__ __launch_bounds__(256) void k_logits(
    const float* __restrict__ qT, const float* __restrict__ kbuf, float* __restrict__ abuf) {
  int bid = blockIdx.x;            // ib*4 + nq
  int ib = bid >> 2;
  int nq = bid & 3;
  __shared__ float klds[100 * 128];
  int tid = threadIdx.x;
  const float* kb_ = kbuf + (long)ib * PP * DD;
  for (int idx = tid; idx < PP * DD; idx += 256) klds[idx] = kb_[idx];
  __syncthreads();
  int wave = tid >> 6, lane = tid & 63;
  for (int nn = 0; nn < 8; ++nn) {
    int n = nq * 32 + nn * 4 + wave;
    const float* qrow = qT + ((long)ib * DD + n) * 100;
    float a1 = 0.f, a2 = 0.f;
#pragma unroll 4
    for (int c = 0; c < 100; ++c) {
      float qv = qrow[c];
      a1 += qv * klds[c * 128 + lane];
      a2 += qv * klds[c * 128 + 64 + lane];
    }
    float mx = fmaxf(a1, a2);
    for (int off = 32; off; off >>= 1) mx = fmaxf(mx, __shfl_xor(mx, off));
    float e1 = __expf(a1 - mx), e2 = __expf(a2 - mx);
    float sm = e1 + e2;
    for (int off = 32; off; off >>= 1) sm += __shfl_xor(sm, off);
    float inv = 1.0f / sm;
    float* arow = abuf + ((long)ib * DD + n) * DD;
    arow[lane] = e1 * inv;
    arow[64 + lane] = e2 * inv;
  }
}

// ---------------- O = V*A^T, then combine: c = 1.33*t1 + 0.33*gamma*O + 0.33*td + 0.33*bu
__global__ __launch_bounds__(256) void k_combine(
    const float* __restrict__ cols, const float* __restrict__ vbuf,
    const float* __restrict__ abuf, const float* __restrict__ ytd,
    const float* __restrict__ ybu, const float* __restrict__ tdbias,
    const float* __restrict__ bub, const float* __restrict__ gamma,
    float* __restrict__ colsn) {
  int bid = blockIdx.x;            // ib*2 + half
  int ib = bid >> 1;
  int half = bid & 1;
  int i = ib >> 4, b = ib & 15;
  __shared__ float aT[128 * 65];   // aT[m][n_local], stride 65 -> conflict-free
  int tid = threadIdx.x;
  const float* ag = abuf + (long)ib * DD * DD;
  for (int idx = tid; idx < 8192; idx += 256) {
    int m = idx & 127;
    int nl = idx >> 7;
    aT[m * 65 + nl] = ag[(long)(half * 64 + nl) * DD + m];
  }
  __syncthreads();
  float gam = gamma[0];
  const float* vb_ = vbuf + (long)ib * PP * DD;
  const float* t1b = cols + (long)ib * PD;
  float* outb = colsn + (long)ib * PD;
  bool has_td = (i < EE - 1);
  bool has_bu = (i > 0);
  const float* ytdr = ytd + ((long)i * BB + b) * PD;
  const float* ybur = ybu + ((long)(i - 1) * BB + b) * PD;
  const long CH = 64L * PD;        // kc-chunk stride in partial buffers
  for (int oi = tid; oi < 6400; oi += 256) {
    int p = oi >> 6;
    int nl = oi & 63;
    int n = half * 64 + nl;
    const float* vrow = vb_ + p * DD;
    float ov = 0.f;
#pragma unroll 4
    for (int m = 0; m < 128; ++m) ov += vrow[m] * aT[m * 65 + nl];
    int od = p * DD + n;
    float t1 = t1b[od];
    float accv = t1 + 0.33f * (gam * ov + t1);
    if (has_td) {
      float y = tdbias[od] + ytdr[od] + ytdr[CH + od] + ytdr[2 * CH + od] + ytdr[3 * CH + od];
      accv += 0.33f * y;
    }
    if (has_bu) {
      float y = bub[od] + ybur[od] + ybur[CH + od] + ybur[2 * CH + od] + ybur[3 * CH + od];
      accv += 0.33f * y;
    }
    outb[od] = accv;
  }
}

// ---------------- final: out[b][d] = mean_p cols[level 4][b][p][d]
__global__ __launch_bounds__(128) void k_mean(const float* __restrict__ cols, float* __restrict__ out) {
  int b = blockIdx.x, d = threadIdx.x;
  const float* base = cols + ((long)4 * BB + b) * PP * DD + d;
  float s = 0.f;
  for (int p = 0; p < PP; ++p) s += base[(long)p * DD];
  out[b * DD + d] = s / 100.0f;
}

extern "C" void kernel_launch(void* const* d_in, const int* in_sizes, int n_in,
                              void* d_out, int out_size, void* d_ws, size_t ws_size,
                              hipStream_t stream) {
  const float* x     = (const float*)d_in[0];
  const float* cnn_w = (const float*)d_in[1];
  const float* cnn_b = (const float*)d_in[2];
  const float* fc_w  = (const float*)d_in[3];
  const float* fc_b  = (const float*)d_in[4];
  const float* td_w  = (const float*)d_in[5];
  const float* td_b  = (const float*)d_in[6];
  const float* bu_w  = (const float*)d_in[7];
  const float* bu_b  = (const float*)d_in[8];
  const float* qw    = (const float*)d_in[9];
  const float* qb    = (const float*)d_in[10];
  const float* kw    = (const float*)d_in[11];
  const float* kb    = (const float*)d_in[12];
  const float* vw    = (const float*)d_in[13];
  const float* vb    = (const float*)d_in[14];
  const float* gamma = (const float*)d_in[15];
  float* out = (float*)d_out;
  float* ws = (float*)d_ws;

  float* cols_a = ws;                     // 1,024,000
  float* cols_b = ws + 1024000;           // 1,024,000
  float* qT     = ws + 2048000;           // 1,024,000
  float* kbuf   = ws + 3072000;           // 1,024,000
  float* vbuf   = ws + 4096000;           // 1,024,000
  float* abuf   = ws + 5120000;           // 1,310,720
  float* ytd    = ws + 6430720;           // 3,276,800
  float* ybu    = ws + 9707520;           // 3,276,800
  float* tdbias = ws + 12984320;          // 12,800
  // packed bf16 region (shorts)
  short* wtd_p  = (short*)(ws + 12997120);          // 163,840,000 shorts
  short* wbu_p  = wtd_p + 163840000;                // 163,840,000 shorts
  short* apack  = wbu_p + 163840000;                // 1,024,000 shorts (+8192 pad)
  size_t need_bytes = (size_t)12997120 * 4 + (163840000ULL * 2 + 1024000ULL + 8192ULL) * 2;
  bool packed = ws_size >= need_bytes;

  k_encoder<<<1600, 128, 0, stream>>>(x, cnn_w, cnn_b, fc_w, fc_b, cols_a);
  k_tdbias<<<50, 256, 0, stream>>>(td_w, td_b, tdbias);

  float* cur = cols_a;
  float* nxt = cols_b;
  for (int t = 0; t < 3; ++t) {
    if (packed) {
      k_packa<<<40, 256, 0, stream>>>(cur, apack);
      if (t == 0)
        k_gemm_f<<<1600, 256, 0, stream>>>(td_w, bu_w, apack, wtd_p, wbu_p, ytd, ybu);
      else
        k_gemm_p<<<1600, 256, 0, stream>>>(apack, wtd_p, wbu_p, ytd, ybu);
    } else {
      k_gemm<<<1600, 256, 0, stream>>>(cur, td_w, bu_w, ytd, ybu);
    }
    k_gconv<<<800, 128, 0, stream>>>(cur, qw, qb, kw, kb, vw, vb, qT, kbuf, vbuf);
    k_logits<<<320, 256, 0, stream>>>(qT, kbuf, abuf);
    k_combine<<<160, 256, 0, stream>>>(cur, vbuf, abuf, ytd, ybu, tdbias, bu_b, gamma, nxt);
    float* tmp = cur; cur = nxt; nxt = tmp;
  }
  k_mean<<<16, 128, 0, stream>>>(cur, out);
}